// Round 2
// 1020.411 us; speedup vs baseline: 1.0114x; 1.0114x over previous
//
#include <hip/hip_runtime.h>
#include <math.h>

// Problem constants (from reference): B=2, N=4096, E=16384, D=64, OUT=64
#define BB 2
#define NN 4096      // 2^12
#define EE 16384     // 2^14
#define DD 64
#define OO 64
// flat element index in [B,N,E]: fe = b*(N*E) + n*E + e ; N*E = 2^26, E = 2^14

// clang native vector type (16 B loads)
typedef unsigned int v4u __attribute__((ext_vector_type(4)));

// ---------------------------------------------------------------------------
// Kernel 1 (R5 rewrite, resubmitted R6 after infra failure): recover
// ri_idx/ro_idx from the one-hot incidence matrices and zero the mi/mo
// accumulators.
//
// Theory: the R3/R4 pattern (nontemporal loads, 32/64 B lane stride) only
// half-uses each 128 B line per instruction and the nt hint blocks L1 merge of
// the partner access -> ~2x HBM transactions per useful byte. This kernel uses
// the m13-proven UNIT-STRIDE pattern: lane reads one contiguous v4u (16 B),
// wave covers 1 KB/instruction. Grid halves: gid < 2^20 streams Ri, rest
// streams Ro; 32 grid-strided iterations each; plain (cacheable) loads.
//
// Inner stores are rare: P(any nonzero in a v4u) = 4/4096 -> wave-level execz
// skips the store block ~94% of iterations.
//
// Each [b,:,e] column has exactly one nonzero -> every idx entry is written
// exactly once (poisoned ws fully overwritten). Must scan all 1.073 GB:
// HBM floor ~170 us at the fill-proven 6.4 TB/s.
// ---------------------------------------------------------------------------
__global__ __launch_bounds__(256) void extract_idx_kernel(
    const v4u* __restrict__ Ri, const v4u* __restrict__ Ro,
    int* __restrict__ ri_idx, int* __restrict__ ro_idx,
    float* __restrict__ mi_mo)   // 2*B*N*D = 1,048,576 floats, contiguous
{
    unsigned gid = blockIdx.x * blockDim.x + threadIdx.x;  // 0 .. 2^21-1
    const unsigned HALF = 1u << 20;                        // threads per matrix

    if (gid < HALF) mi_mo[gid] = 0.0f;   // covers all 2^20 mi+mo floats

    const v4u* __restrict__ src = (gid < HALF) ? Ri : Ro;
    int* __restrict__ idx       = (gid < HALF) ? ri_idx : ro_idx;
    unsigned lgid = gid & (HALF - 1);

    // 2^25 v4u per matrix / 2^20 threads = 32 iterations, stride 2^20 v4u.
    #pragma unroll 4
    for (unsigned k = 0; k < 32; ++k) {
        unsigned i = lgid + k * HALF;        // unit lane stride within a wave
        v4u a = src[i];
        if (a.x | a.y | a.z | a.w) {         // rare (p ~ 1/1024 per lane)
            unsigned fe = i * 4u;            // flat element index in [B,N,E]
            int e = (int)(fe & (EE - 1));    // 4 consecutive e's, same (b,n)
            int n = (int)((fe >> 14) & (NN - 1));
            int b = (int)(fe >> 26);
            int base = b * EE + e;
            if (a.x) idx[base + 0] = n;
            if (a.y) idx[base + 1] = n;
            if (a.z) idx[base + 2] = n;
            if (a.w) idx[base + 3] = n;
        }
    }
}

// ---------------------------------------------------------------------------
// Kernel 2: edge-weighted scatter-add (unchanged — est. 30-50 us).
// mi[b,ri,:] += w * X[b,ro,:];  mo[b,ro,:] += w * X[b,ri,:]
// 64 lanes per edge (one per feature). Coalesced gathers and atomic targets;
// avg 4 edges/node -> low atomic contention.
// ---------------------------------------------------------------------------
__global__ __launch_bounds__(256) void scatter_kernel(
    const float* __restrict__ X, const float* __restrict__ ew,
    const int* __restrict__ ri_idx, const int* __restrict__ ro_idx,
    float* __restrict__ mi, float* __restrict__ mo)
{
    int t = blockIdx.x * blockDim.x + threadIdx.x;
    int edge = t >> 6;                 // global edge id in [0, B*E)
    int lane = t & 63;
    if (edge >= BB * EE) return;
    int b = edge >> 14;                // E = 2^14
    float w = ew[edge];
    int ri = ri_idx[edge];
    int ro = ro_idx[edge];
    const float* xb = X + (size_t)b * NN * DD;
    float xro = xb[ro * DD + lane];
    float xri = xb[ri * DD + lane];
    float* mib = mi + (size_t)b * NN * DD;
    float* mob = mo + (size_t)b * NN * DD;
    atomicAdd(&mib[ri * DD + lane], w * xro);
    atomicAdd(&mob[ro * DD + lane], w * xri);
}

// ---------------------------------------------------------------------------
// Kernel 3: per-node MLP, one WAVE per node, lane j = output channel
// (unchanged — est. 15-20 us, L1-hot weights, full occupancy).
// ---------------------------------------------------------------------------
__global__ __launch_bounds__(256) void mlp_kernel(
    const float* __restrict__ X, const float* __restrict__ mi,
    const float* __restrict__ mo,
    const float* __restrict__ W1, const float* __restrict__ b1,
    const float* __restrict__ W2, const float* __restrict__ b2,
    float* __restrict__ out)
{
    int wid = (blockIdx.x * blockDim.x + threadIdx.x) >> 6;   // node id
    int lane = threadIdx.x & 63;
    if (wid >= BB * NN) return;

    float acc = b1[lane];
    const float* srcs[3];
    srcs[0] = mi + (size_t)wid * DD;
    srcs[1] = mo + (size_t)wid * DD;
    srcs[2] = X  + (size_t)wid * DD;

    for (int part = 0; part < 3; ++part) {
        float fv = srcs[part][lane];          // lane k holds feat[k]
        const float* wbase = W1 + (size_t)part * DD * OO;
        #pragma unroll
        for (int k = 0; k < DD; ++k) {
            float fk = __shfl(fv, k, 64);
            acc += fk * wbase[k * OO + lane]; // coalesced row, L1-hot
        }
    }
    float h = tanhf(acc);

    float acc2 = b2[lane];
    #pragma unroll
    for (int k = 0; k < OO; ++k) {
        float hk = __shfl(h, k, 64);
        acc2 += hk * W2[k * OO + lane];
    }
    out[(size_t)wid * OO + lane] = tanhf(acc2);
}

// ---------------------------------------------------------------------------
extern "C" void kernel_launch(void* const* d_in, const int* in_sizes, int n_in,
                              void* d_out, int out_size, void* d_ws, size_t ws_size,
                              hipStream_t stream)
{
    const float* X  = (const float*)d_in[0];   // [B,N,D]
    const float* ew = (const float*)d_in[1];   // [B,E]
    const float* Ri = (const float*)d_in[2];   // [B,N,E]
    const float* Ro = (const float*)d_in[3];   // [B,N,E]
    const float* W1 = (const float*)d_in[4];   // [3D,OUT]
    const float* b1 = (const float*)d_in[5];   // [OUT]
    const float* W2 = (const float*)d_in[6];   // [OUT,OUT]
    const float* b2 = (const float*)d_in[7];   // [OUT]
    float* out = (float*)d_out;                // [B,N,OUT]

    // workspace layout (ws re-poisoned to 0xAA each call -> re-init all of it)
    float* mi = (float*)d_ws;                            // 2 MB
    float* mo = mi + (size_t)BB * NN * DD;               // 2 MB
    int* ri_idx = (int*)(mo + (size_t)BB * NN * DD);     // 128 KB
    int* ro_idx = ri_idx + BB * EE;                      // 128 KB

    // 2^21 threads: first half streams Ri (and zeroes mi/mo), second half Ro
    extract_idx_kernel<<<8192, 256, 0, stream>>>(
        (const v4u*)Ri, (const v4u*)Ro, ri_idx, ro_idx, mi);

    scatter_kernel<<<(BB * EE * 64) / 256, 256, 0, stream>>>(
        X, ew, ri_idx, ro_idx, mi, mo);

    mlp_kernel<<<(BB * NN * 64) / 256, 256, 0, stream>>>(
        X, mi, mo, W1, b1, W2, b2, out);
}